// Round 8
// baseline (8992.996 us; speedup 1.0000x reference)
//
#include <hip/hip_runtime.h>

typedef __attribute__((ext_vector_type(4))) float f32x4;
typedef __attribute__((ext_vector_type(8))) short short8;
typedef __attribute__((ext_vector_type(4))) short short4_t;
typedef unsigned long long ull;

__device__ __forceinline__ short f2bf(float f) {
  unsigned u = __float_as_uint(f);
  u += 0x7fffu + ((u >> 16) & 1u);   // round-to-nearest-even
  return (short)(u >> 16);
}

__device__ __forceinline__ float tanh_fast(float x) {
  float e = __expf(2.0f * x);
  return 1.0f - __fdividef(2.0f, e + 1.0f);
}

// ---------------------------------------------------------------- convert W,U -> bf16
__global__ __launch_bounds__(256) void convert_wu(
    const float* __restrict__ W, const float* __restrict__ U,
    short* __restrict__ Wb, short* __restrict__ Ub) {
  int i = blockIdx.x * 256 + threadIdx.x;
  if (i < 65536) {
    f32x4 v = ((const f32x4*)W)[i];
    short4_t s;
    s.x = f2bf(v.x); s.y = f2bf(v.y); s.z = f2bf(v.z); s.w = f2bf(v.w);
    ((short4_t*)Wb)[i] = s;
  } else if (i < 98304) {
    int k = i - 65536;
    f32x4 v = ((const f32x4*)U)[k];
    short4_t s;
    s.x = f2bf(v.x); s.y = f2bf(v.y); s.z = f2bf(v.z); s.w = f2bf(v.w);
    ((short4_t*)Ub)[k] = s;
  }
}

// ---------------------------------------------------------------- xu = x @ U^T  (bf16 MFMA)
__global__ __launch_bounds__(256) void xu_gemm(
    const float* __restrict__ x, const short* __restrict__ Ub,
    float* __restrict__ out) {
  __shared__ __attribute__((aligned(16))) short a_lds[128][272];
  __shared__ __attribute__((aligned(16))) short b_lds[128][272];
  const int tid = threadIdx.x;
  const int mb = blockIdx.x >> 2;
  const int nb = blockIdx.x & 3;

  const float* xb = x + (size_t)mb * (128 * 256);
  for (int c = 0; c < 32; ++c) {
    int idx = c * 256 + tid;
    int r = idx >> 6, c4 = idx & 63;
    f32x4 v = ((const f32x4*)xb)[idx];
    short4_t s;
    s.x = f2bf(v.x); s.y = f2bf(v.y); s.z = f2bf(v.z); s.w = f2bf(v.w);
    *(short4_t*)&a_lds[r][c4 * 4] = s;
  }
  const short* ub = Ub + nb * (128 * 256);
  for (int c = 0; c < 16; ++c) {
    int idx = c * 256 + tid;
    int r = idx >> 5, ch = idx & 31;
    *(short8*)&b_lds[r][ch * 8] = ((const short8*)ub)[idx];
  }
  __syncthreads();

  const int lane = tid & 63, wave = tid >> 6;
  const int wr = wave >> 1, wc = wave & 1;
  const int lr = lane & 15, lk = lane >> 4;
  const f32x4 zero = {0.f, 0.f, 0.f, 0.f};
  f32x4 acc[4][4];
  #pragma unroll
  for (int mt = 0; mt < 4; ++mt)
    #pragma unroll
    for (int nt = 0; nt < 4; ++nt) acc[mt][nt] = zero;

  #pragma unroll
  for (int kt = 0; kt < 8; ++kt) {
    const int k = kt * 32 + lk * 8;
    short8 a[4], b[4];
    #pragma unroll
    for (int mt = 0; mt < 4; ++mt)
      a[mt] = *(const short8*)&a_lds[wr * 64 + mt * 16 + lr][k];
    #pragma unroll
    for (int nt = 0; nt < 4; ++nt)
      b[nt] = *(const short8*)&b_lds[wc * 64 + nt * 16 + lr][k];
    #pragma unroll
    for (int mt = 0; mt < 4; ++mt)
      #pragma unroll
      for (int nt = 0; nt < 4; ++nt)
        acc[mt][nt] = __builtin_amdgcn_mfma_f32_16x16x32_bf16(a[mt], b[nt], acc[mt][nt], 0, 0, 0);
  }

  #pragma unroll
  for (int mt = 0; mt < 4; ++mt)
    #pragma unroll
    for (int nt = 0; nt < 4; ++nt)
      #pragma unroll
      for (int q = 0; q < 4; ++q) {
        int row = mb * 128 + wr * 64 + mt * 16 + lk * 4 + q;
        int col = nb * 128 + wc * 64 + nt * 16 + lr;
        out[(size_t)row * 512 + col] = acc[mt][nt][q];
      }
}

// ---------------------------------------------------------------- recurrence scan
// 16 blocks = 4 batch-groups x 4 j-slices (128 cols). Each WAVE owns 16 cols:
// full-k W slice = 16 x short8 = 64 VGPRs -> W entirely register-resident,
// ZERO per-step W traffic (R1/R2/R6/R7 were L1-BW-bound on ~300-380 KB/step
// of W through L1; three different schemes all landed at ~3.0-3.9 us/step).
// Per-step tanh(h) exchange between the 4 slice-blocks of a group goes through
// L3 via agent-scope RELAXED atomics (sc-flagged, execute at coherence point;
// NO threadfence -> no L2 flush, which was R5's 6.5us/step failure).
// Ordering: data-stores -> s_waitcnt vmcnt(0) -> barrier -> counter fetch_add;
// readers spin counter >= 4t then load. Double-buffered exchange is race-free:
// a writer reaches parity p's rewrite only after all readers' publishes, which
// program-order-follow their reads.
__global__ __launch_bounds__(512, 2) void rnn_scan(
    const short* __restrict__ Wb, float* __restrict__ out,
    short* __restrict__ ex, unsigned* __restrict__ bar) {
  __shared__ short tp[8][16][16];       // per-wave transpose scratch (4 KB)
  const int tid = threadIdx.x;
  const int g = blockIdx.x >> 2;        // batch group: rows [16g, 16g+16)
  const int s = blockIdx.x & 3;         // j-slice: cols [128s, 128s+128)
  const int lane = tid & 63, wave = tid >> 6;
  const int lr = lane & 15, lk = lane >> 4;
  const int c0 = s * 128 + wave * 16;   // wave's 16 output cols

  // W slice in registers: wreg[kt] = W[c0+lr][kt*32+lk*8 .. +8]  (64 VGPRs)
  short8 wreg[16];
  {
    const short* wrow = Wb + (c0 + lr) * 512 + lk * 8;
    #pragma unroll
    for (int kt = 0; kt < 16; ++kt) {
      wreg[kt] = *(const short8*)(wrow + kt * 32);
      asm volatile("" : "+v"(wreg[kt]));   // block remat/sink
    }
  }

  // exchange buffers (ull granularity): per parity 4 groups x [16][512] bf16
  ull* exU = (ull*)ex;
  ull* exg0 = exU + (size_t)g * 2048;          // parity 0
  ull* exg1 = exU + 8192 + (size_t)g * 2048;   // parity 1
  unsigned* cnt = bar + g * 64;                // one counter per group (256B apart)

  float h[4] = {0.f, 0.f, 0.f, 0.f};
  const size_t base = (size_t)(g * 16 + lk * 4) * 524288 + c0 + lr;

  // prefetch xu[t=0]
  float xun[4];
  {
    const float* p = out + base;
    #pragma unroll
    for (int q = 0; q < 4; ++q) xun[q] = p[(size_t)q * 524288];
  }

  for (int t = 0; t < 1024; ++t) {
    // ---- wait for tanh(h_t) of all 4 slices (t=0: ex parity0 pre-zeroed) ----
    if (t > 0) {
      if (tid == 0) {
        while (__hip_atomic_load(cnt, __ATOMIC_RELAXED, __HIP_MEMORY_SCOPE_AGENT)
               < 4u * (unsigned)t) {}
      }
      __syncthreads();
    }

    // ---- acc = xu_t + tanh(h_t) @ W^T (A-frags loaded from L3 exchange) ----
    const ull* er = ((t & 1) ? exg1 : exg0) + (size_t)lr * 128 + lk * 2;
    f32x4 accA = {xun[0], xun[1], xun[2], xun[3]};
    f32x4 accB = {0.f, 0.f, 0.f, 0.f};
    #pragma unroll
    for (int kt = 0; kt < 16; kt += 2) {
      union { ull u[2]; short8 s8; } a0, a1;
      a0.u[0] = __hip_atomic_load(er + kt * 8,     __ATOMIC_RELAXED, __HIP_MEMORY_SCOPE_AGENT);
      a0.u[1] = __hip_atomic_load(er + kt * 8 + 1, __ATOMIC_RELAXED, __HIP_MEMORY_SCOPE_AGENT);
      a1.u[0] = __hip_atomic_load(er + kt * 8 + 8, __ATOMIC_RELAXED, __HIP_MEMORY_SCOPE_AGENT);
      a1.u[1] = __hip_atomic_load(er + kt * 8 + 9, __ATOMIC_RELAXED, __HIP_MEMORY_SCOPE_AGENT);
      accA = __builtin_amdgcn_mfma_f32_16x16x32_bf16(a0.s8, wreg[kt],     accA, 0, 0, 0);
      accB = __builtin_amdgcn_mfma_f32_16x16x32_bf16(a1.s8, wreg[kt + 1], accB, 0, 0, 0);
    }

    // ---- h' = 0.9h + 0.1(accA+accB); store h'; prefetch xu_{t+1} ----
    float* po = out + base + (size_t)t * 512;
    #pragma unroll
    for (int q = 0; q < 4; ++q) {
      float v = 0.9f * h[q] + 0.1f * (accA[q] + accB[q]);
      h[q] = v;
      po[(size_t)q * 524288] = v;
    }
    {
      int tn = t + 1; if (tn > 1023) tn = 1023;
      const float* pn = out + base + (size_t)tn * 512;
      #pragma unroll
      for (int q = 0; q < 4; ++q) xun[q] = pn[(size_t)q * 524288];
    }

    // ---- publish tanh(h_{t+1}) for next step ----
    if (t < 1023) {
      // per-wave transpose: tp[w][row][col16], row = batch row, col = j-col
      #pragma unroll
      for (int q = 0; q < 4; ++q)
        tp[wave][lk * 4 + q][lr] = f2bf(tanh_fast(h[q]));
      // lanes 0..31: row = l>>1, col-half = l&1 -> two 8B agent-scope stores
      ull* ew = ((t & 1) ? exg0 : exg1);       // parity (t+1)&1
      if (lane < 32) {
        int r = lane >> 1, hf = lane & 1;
        ull d0 = *(const ull*)&tp[wave][r][hf * 8];
        ull d1 = *(const ull*)&tp[wave][r][hf * 8 + 4];
        ull* dst = ew + (size_t)r * 128 + (c0 >> 2) + hf * 2;
        __hip_atomic_store(dst,     d0, __ATOMIC_RELAXED, __HIP_MEMORY_SCOPE_AGENT);
        __hip_atomic_store(dst + 1, d1, __ATOMIC_RELAXED, __HIP_MEMORY_SCOPE_AGENT);
      }
      asm volatile("s_waitcnt vmcnt(0)" ::: "memory");
      __syncthreads();                         // all waves' stores drained
      if (tid == 0)
        __hip_atomic_fetch_add(cnt, 1u, __ATOMIC_RELAXED, __HIP_MEMORY_SCOPE_AGENT);
    }
  }
}

// ----------------------------------------------------------------
extern "C" void kernel_launch(void* const* d_in, const int* in_sizes, int n_in,
                              void* d_out, int out_size, void* d_ws, size_t ws_size,
                              hipStream_t stream) {
  (void)in_sizes; (void)n_in; (void)out_size; (void)ws_size;
  const float* x = (const float*)d_in[0];   // [64,1024,256]
  const float* W = (const float*)d_in[1];   // [512,512]
  const float* U = (const float*)d_in[2];   // [512,256]
  float* out = (float*)d_out;               // [64,1024,512]
  short* Wb = (short*)d_ws;                 // 512KB bf16 W
  short* Ub = Wb + 262144;                  // 256KB bf16 U
  short* ex = Ub + 131072;                  // 128KB exchange: [2][4][16][512] bf16
  unsigned* bar = (unsigned*)(ex + 65536);  // 1KB counters (4 groups x 256B)

  hipMemsetAsync((void*)ex, 0, 65536 * 2 + 1024, stream);  // parity0 + parity1 + counters
  convert_wu<<<384, 256, 0, stream>>>(W, U, Wb, Ub);
  xu_gemm<<<2048, 256, 0, stream>>>(x, Ub, out);
  rnn_scan<<<16, 512, 0, stream>>>(Wb, out, ex, bar);
}

// Round 9
// 4591.727 us; speedup vs baseline: 1.9585x; 1.9585x over previous
//
#include <hip/hip_runtime.h>

typedef __attribute__((ext_vector_type(4))) float f32x4;
typedef __attribute__((ext_vector_type(8))) short short8;
typedef __attribute__((ext_vector_type(4))) short short4_t;

__device__ __forceinline__ short f2bf(float f) {
  unsigned u = __float_as_uint(f);
  u += 0x7fffu + ((u >> 16) & 1u);   // round-to-nearest-even
  return (short)(u >> 16);
}

__device__ __forceinline__ float tanh_fast(float x) {
  float e = __expf(2.0f * x);
  return 1.0f - __fdividef(2.0f, e + 1.0f);
}

// ---------------------------------------------------------------- convert W,U -> bf16
__global__ __launch_bounds__(256) void convert_wu(
    const float* __restrict__ W, const float* __restrict__ U,
    short* __restrict__ Wb, short* __restrict__ Ub) {
  int i = blockIdx.x * 256 + threadIdx.x;
  if (i < 65536) {
    f32x4 v = ((const f32x4*)W)[i];
    short4_t s;
    s.x = f2bf(v.x); s.y = f2bf(v.y); s.z = f2bf(v.z); s.w = f2bf(v.w);
    ((short4_t*)Wb)[i] = s;
  } else if (i < 98304) {
    int k = i - 65536;
    f32x4 v = ((const f32x4*)U)[k];
    short4_t s;
    s.x = f2bf(v.x); s.y = f2bf(v.y); s.z = f2bf(v.z); s.w = f2bf(v.w);
    ((short4_t*)Ub)[k] = s;
  }
}

// ---------------------------------------------------------------- xu = x @ U^T  (bf16 MFMA)
__global__ __launch_bounds__(256) void xu_gemm(
    const float* __restrict__ x, const short* __restrict__ Ub,
    float* __restrict__ out) {
  __shared__ __attribute__((aligned(16))) short a_lds[128][272];
  __shared__ __attribute__((aligned(16))) short b_lds[128][272];
  const int tid = threadIdx.x;
  const int mb = blockIdx.x >> 2;
  const int nb = blockIdx.x & 3;

  const float* xb = x + (size_t)mb * (128 * 256);
  for (int c = 0; c < 32; ++c) {
    int idx = c * 256 + tid;
    int r = idx >> 6, c4 = idx & 63;
    f32x4 v = ((const f32x4*)xb)[idx];
    short4_t s;
    s.x = f2bf(v.x); s.y = f2bf(v.y); s.z = f2bf(v.z); s.w = f2bf(v.w);
    *(short4_t*)&a_lds[r][c4 * 4] = s;
  }
  const short* ub = Ub + nb * (128 * 256);
  for (int c = 0; c < 16; ++c) {
    int idx = c * 256 + tid;
    int r = idx >> 5, ch = idx & 31;
    *(short8*)&b_lds[r][ch * 8] = ((const short8*)ub)[idx];
  }
  __syncthreads();

  const int lane = tid & 63, wave = tid >> 6;
  const int wr = wave >> 1, wc = wave & 1;
  const int lr = lane & 15, lk = lane >> 4;
  const f32x4 zero = {0.f, 0.f, 0.f, 0.f};
  f32x4 acc[4][4];
  #pragma unroll
  for (int mt = 0; mt < 4; ++mt)
    #pragma unroll
    for (int nt = 0; nt < 4; ++nt) acc[mt][nt] = zero;

  #pragma unroll
  for (int kt = 0; kt < 8; ++kt) {
    const int k = kt * 32 + lk * 8;
    short8 a[4], b[4];
    #pragma unroll
    for (int mt = 0; mt < 4; ++mt)
      a[mt] = *(const short8*)&a_lds[wr * 64 + mt * 16 + lr][k];
    #pragma unroll
    for (int nt = 0; nt < 4; ++nt)
      b[nt] = *(const short8*)&b_lds[wc * 64 + nt * 16 + lr][k];
    #pragma unroll
    for (int mt = 0; mt < 4; ++mt)
      #pragma unroll
      for (int nt = 0; nt < 4; ++nt)
        acc[mt][nt] = __builtin_amdgcn_mfma_f32_16x16x32_bf16(a[mt], b[nt], acc[mt][nt], 0, 0, 0);
  }

  #pragma unroll
  for (int mt = 0; mt < 4; ++mt)
    #pragma unroll
    for (int nt = 0; nt < 4; ++nt)
      #pragma unroll
      for (int q = 0; q < 4; ++q) {
        int row = mb * 128 + wr * 64 + mt * 16 + lk * 4 + q;
        int col = nb * 128 + wc * 64 + nt * 16 + lr;
        out[(size_t)row * 512 + col] = acc[mt][nt][q];
      }
}

// ---------------------------------------------------------------- recurrence scan
// 4 blocks x 256 threads (4 waves = 1 wave/SIMD!). Register-pool arithmetic
// (m69: 512 VGPR/SIMD pool) says: 8-wave blocks cap each wave at <=256 regs
// (allocator chose 128 every time, R1-R8); 4-wave blocks allow ~450+ (m08).
// LDS (156KB) forces 1 block/CU anyway, so 1 wave/SIMD costs nothing extra.
// Each wave owns 128 j-cols. W split: k[0,288) in 288 pinned VGPRs,
// k[288,416) in LDS 139KB, k[416,512) streamed 96KB/step (rotating 32-reg
// buffer, each load issued a phase before use). Stream ~1600cyc bounds step.
__global__ __launch_bounds__(256, 1)
__attribute__((amdgpu_waves_per_eu(1, 1)))
void rnn_scan(const short* __restrict__ Wb, float* __restrict__ out) {
  __shared__ __attribute__((aligned(16))) short w_lds[512][136];  // k 288..416
  __shared__ __attribute__((aligned(16))) short a_lds[16][520];   // tanh(h) bf16
  const int tid = threadIdx.x;
  const int g = blockIdx.x;             // batch rows [16g, 16g+16)
  const int lane = tid & 63, wave = tid >> 6;
  const int jb = wave * 128;            // wave's j-col block
  const int lr = lane & 15, lk = lane >> 4;

  // per-jt stream/init pointers (row = jb + jt*16 + lr, k-base = lk*8)
  const short* ps[8];
  #pragma unroll
  for (int jt = 0; jt < 8; ++jt)
    ps[jt] = Wb + (jb + jt * 16 + lr) * 512 + lk * 8;

  // register-resident W: kt 0..8 (k in [0,288)), 288 VGPRs, pinned
  short8 wreg[8][9];
  #pragma unroll
  for (int jt = 0; jt < 8; ++jt)
    #pragma unroll
    for (int kt = 0; kt < 9; ++kt) {
      wreg[jt][kt] = *(const short8*)(ps[jt] + kt * 32);
      asm volatile("" : "+v"(wreg[jt][kt]));   // block remat/sink
    }

  // LDS W: k in [288,416): 512 rows x 16 short8-chunks = 32 iters of 256 thr
  for (int c = 0; c < 32; ++c) {
    int idx = c * 256 + tid;
    int j = idx >> 4, ch = idx & 15;
    *(short8*)&w_lds[j][ch * 8] = *(const short8*)(Wb + j * 512 + 288 + ch * 8);
  }

  float h[8][4];
  #pragma unroll
  for (int jt = 0; jt < 8; ++jt)
    #pragma unroll
    for (int q = 0; q < 4; ++q) h[jt][q] = 0.f;

  const size_t base = (size_t)(g * 16 + lk * 4) * 524288 + jb + lr;
  __syncthreads();

  f32x4 acc[8];
  // prologue: acc <- xu[t=0]
  {
    const float* p = out + base;
    #pragma unroll
    for (int jt = 0; jt < 8; ++jt)
      #pragma unroll
      for (int q = 0; q < 4; ++q)
        acc[jt][q] = p[(size_t)q * 524288 + jt * 16];
  }

  // stream buffer, preloaded with kt=13 (k 416..448)
  short8 sbuf[8];
  #pragma unroll
  for (int jt = 0; jt < 8; ++jt) sbuf[jt] = *(const short8*)(ps[jt] + 13 * 32);

  for (int t = 0; t < 1024; ++t) {
    // A = tanh(h) -> bf16 staging (stream kt13 already in flight from tail)
    #pragma unroll
    for (int jt = 0; jt < 8; ++jt)
      #pragma unroll
      for (int q = 0; q < 4; ++q)
        a_lds[lk * 4 + q][jb + jt * 16 + lr] = f2bf(tanh_fast(h[jt][q]));
    __syncthreads();

    // ---- MFMA phase; order chosen to hide stream-load latency ----
    // kt13 (stream, preloaded) then refill -> kt14
    {
      short8 a8 = *(const short8*)&a_lds[lr][13 * 32 + lk * 8];
      #pragma unroll
      for (int jt = 0; jt < 8; ++jt)
        acc[jt] = __builtin_amdgcn_mfma_f32_16x16x32_bf16(a8, sbuf[jt], acc[jt], 0, 0, 0);
      #pragma unroll
      for (int jt = 0; jt < 8; ++jt) sbuf[jt] = *(const short8*)(ps[jt] + 14 * 32);
    }
    // kt 9..12 (LDS) while kt14 arrives
    #pragma unroll
    for (int kt = 9; kt < 13; ++kt) {
      short8 a8 = *(const short8*)&a_lds[lr][kt * 32 + lk * 8];
      #pragma unroll
      for (int jt = 0; jt < 8; ++jt) {
        short8 b = *(const short8*)&w_lds[jb + jt * 16 + lr][(kt - 9) * 32 + lk * 8];
        acc[jt] = __builtin_amdgcn_mfma_f32_16x16x32_bf16(a8, b, acc[jt], 0, 0, 0);
      }
    }
    // kt14 (stream) then refill -> kt15
    {
      short8 a8 = *(const short8*)&a_lds[lr][14 * 32 + lk * 8];
      #pragma unroll
      for (int jt = 0; jt < 8; ++jt)
        acc[jt] = __builtin_amdgcn_mfma_f32_16x16x32_bf16(a8, sbuf[jt], acc[jt], 0, 0, 0);
      #pragma unroll
      for (int jt = 0; jt < 8; ++jt) sbuf[jt] = *(const short8*)(ps[jt] + 15 * 32);
    }
    // kt 0..8 (registers) while kt15 arrives
    #pragma unroll
    for (int kt = 0; kt < 9; ++kt) {
      short8 a8 = *(const short8*)&a_lds[lr][kt * 32 + lk * 8];
      #pragma unroll
      for (int jt = 0; jt < 8; ++jt)
        acc[jt] = __builtin_amdgcn_mfma_f32_16x16x32_bf16(a8, wreg[jt][kt], acc[jt], 0, 0, 0);
    }
    // kt15 (stream) then refill -> kt13 for NEXT step (long lead time)
    {
      short8 a8 = *(const short8*)&a_lds[lr][15 * 32 + lk * 8];
      #pragma unroll
      for (int jt = 0; jt < 8; ++jt)
        acc[jt] = __builtin_amdgcn_mfma_f32_16x16x32_bf16(a8, sbuf[jt], acc[jt], 0, 0, 0);
      #pragma unroll
      for (int jt = 0; jt < 8; ++jt) sbuf[jt] = *(const short8*)(ps[jt] + 13 * 32);
    }

    // h' = 0.9*h + 0.1*acc; store in place over xu[t]
    float* po = out + base + (size_t)t * 512;
    #pragma unroll
    for (int jt = 0; jt < 8; ++jt)
      #pragma unroll
      for (int q = 0; q < 4; ++q) {
        float v = 0.9f * h[jt][q] + 0.1f * acc[jt][q];
        h[jt][q] = v;
        po[(size_t)q * 524288 + jt * 16] = v;
      }
    __syncthreads();  // a_lds reads done before next iteration's writes

    // tail: prefetch next step's xu into acc (hides L3 latency)
    int tn = t + 1; if (tn > 1023) tn = 1023;
    const float* pn = out + base + (size_t)tn * 512;
    #pragma unroll
    for (int jt = 0; jt < 8; ++jt)
      #pragma unroll
      for (int q = 0; q < 4; ++q)
        acc[jt][q] = pn[(size_t)q * 524288 + jt * 16];
  }
}

// ----------------------------------------------------------------
extern "C" void kernel_launch(void* const* d_in, const int* in_sizes, int n_in,
                              void* d_out, int out_size, void* d_ws, size_t ws_size,
                              hipStream_t stream) {
  (void)in_sizes; (void)n_in; (void)out_size; (void)ws_size;
  const float* x = (const float*)d_in[0];
  const float* W = (const float*)d_in[1];
  const float* U = (const float*)d_in[2];
  float* out = (float*)d_out;
  short* Wb = (short*)d_ws;
  short* Ub = Wb + 512 * 512;

  convert_wu<<<384, 256, 0, stream>>>(W, U, Wb, Ub);
  xu_gemm<<<2048, 256, 0, stream>>>(x, Ub, out);
  rnn_scan<<<4, 256, 0, stream>>>(Wb, out);
}

// Round 10
// 4325.915 us; speedup vs baseline: 2.0789x; 1.0614x over previous
//
#include <hip/hip_runtime.h>

typedef __attribute__((ext_vector_type(4))) float f32x4;
typedef __attribute__((ext_vector_type(8))) short short8;
typedef __attribute__((ext_vector_type(4))) short short4_t;

__device__ __forceinline__ short f2bf(float f) {
  unsigned u = __float_as_uint(f);
  u += 0x7fffu + ((u >> 16) & 1u);   // round-to-nearest-even
  return (short)(u >> 16);
}

__device__ __forceinline__ float tanh_fast(float x) {
  float e = __expf(2.0f * x);
  return 1.0f - __fdividef(2.0f, e + 1.0f);
}

// ---------------------------------------------------------------- convert W,U -> bf16
__global__ __launch_bounds__(256) void convert_wu(
    const float* __restrict__ W, const float* __restrict__ U,
    short* __restrict__ Wb, short* __restrict__ Ub) {
  int i = blockIdx.x * 256 + threadIdx.x;
  if (i < 65536) {
    f32x4 v = ((const f32x4*)W)[i];
    short4_t s;
    s.x = f2bf(v.x); s.y = f2bf(v.y); s.z = f2bf(v.z); s.w = f2bf(v.w);
    ((short4_t*)Wb)[i] = s;
  } else if (i < 98304) {
    int k = i - 65536;
    f32x4 v = ((const f32x4*)U)[k];
    short4_t s;
    s.x = f2bf(v.x); s.y = f2bf(v.y); s.z = f2bf(v.z); s.w = f2bf(v.w);
    ((short4_t*)Ub)[k] = s;
  }
}

// ---------------------------------------------------------------- xu = x @ U^T  (bf16 MFMA)
__global__ __launch_bounds__(256) void xu_gemm(
    const float* __restrict__ x, const short* __restrict__ Ub,
    float* __restrict__ out) {
  __shared__ __attribute__((aligned(16))) short a_lds[128][272];
  __shared__ __attribute__((aligned(16))) short b_lds[128][272];
  const int tid = threadIdx.x;
  const int mb = blockIdx.x >> 2;
  const int nb = blockIdx.x & 3;

  const float* xb = x + (size_t)mb * (128 * 256);
  for (int c = 0; c < 32; ++c) {
    int idx = c * 256 + tid;
    int r = idx >> 6, c4 = idx & 63;
    f32x4 v = ((const f32x4*)xb)[idx];
    short4_t s;
    s.x = f2bf(v.x); s.y = f2bf(v.y); s.z = f2bf(v.z); s.w = f2bf(v.w);
    *(short4_t*)&a_lds[r][c4 * 4] = s;
  }
  const short* ub = Ub + nb * (128 * 256);
  for (int c = 0; c < 16; ++c) {
    int idx = c * 256 + tid;
    int r = idx >> 5, ch = idx & 31;
    *(short8*)&b_lds[r][ch * 8] = ((const short8*)ub)[idx];
  }
  __syncthreads();

  const int lane = tid & 63, wave = tid >> 6;
  const int wr = wave >> 1, wc = wave & 1;
  const int lr = lane & 15, lk = lane >> 4;
  const f32x4 zero = {0.f, 0.f, 0.f, 0.f};
  f32x4 acc[4][4];
  #pragma unroll
  for (int mt = 0; mt < 4; ++mt)
    #pragma unroll
    for (int nt = 0; nt < 4; ++nt) acc[mt][nt] = zero;

  #pragma unroll
  for (int kt = 0; kt < 8; ++kt) {
    const int k = kt * 32 + lk * 8;
    short8 a[4], b[4];
    #pragma unroll
    for (int mt = 0; mt < 4; ++mt)
      a[mt] = *(const short8*)&a_lds[wr * 64 + mt * 16 + lr][k];
    #pragma unroll
    for (int nt = 0; nt < 4; ++nt)
      b[nt] = *(const short8*)&b_lds[wc * 64 + nt * 16 + lr][k];
    #pragma unroll
    for (int mt = 0; mt < 4; ++mt)
      #pragma unroll
      for (int nt = 0; nt < 4; ++nt)
        acc[mt][nt] = __builtin_amdgcn_mfma_f32_16x16x32_bf16(a[mt], b[nt], acc[mt][nt], 0, 0, 0);
  }

  #pragma unroll
  for (int mt = 0; mt < 4; ++mt)
    #pragma unroll
    for (int nt = 0; nt < 4; ++nt)
      #pragma unroll
      for (int q = 0; q < 4; ++q) {
        int row = mb * 128 + wr * 64 + mt * 16 + lk * 4 + q;
        int col = nb * 128 + wc * 64 + nt * 16 + lr;
        out[(size_t)row * 512 + col] = acc[mt][nt][q];
      }
}

// ---------------------------------------------------------------- recurrence scan
// 4 blocks x 256 threads (4 waves = 1 wave/SIMD, 1 block/CU via 148KB LDS).
// R9's counter proved the gfx950 per-wave budget is 256 ARCH VGPRs + 256
// AGPRs (unified file, m69 pool 512/SIMD): asking 424 arch spilled. So W
// lives in BOTH halves, all asks legal this time:
//   kt 0..7  (k<256), jt 0..6 : 224 AGPRs ("+a" pin; gfx950 MFMA reads AGPR
//                               B-operands directly, ISA sec 10)
//   kt 0..7,  jt 7            : 32 arch VGPRs ("+v" pin)
//   kt 8..11 (k 256..384)     : LDS, 131KB
//   kt 12..15 (k 384..512)    : streamed from L2, 128KB/step, depth-2 rotation
// Arch ~205 <= 244, AGPR 224 <= 256. L1 traffic/step: 320KB (R7) -> 192KB.
// (R4's NaN was this idea at an ILLEGAL budget: 192 AGPR + 124 arch in a
// 256-combined 2-wave/SIMD slot -> forced AGPR spill machinery.)
__global__ __launch_bounds__(256, 1)
void rnn_scan(const short* __restrict__ Wb, float* __restrict__ out) {
  __shared__ __attribute__((aligned(16))) short w_lds[512][136];  // k 256..384
  __shared__ __attribute__((aligned(16))) short a_lds[16][520];   // tanh(h) bf16
  const int tid = threadIdx.x;
  const int g = blockIdx.x;             // batch rows [16g, 16g+16)
  const int lane = tid & 63, wave = tid >> 6;
  const int jb = wave * 128;            // wave's 128 j-cols
  const int lr = lane & 15, lk = lane >> 4;

  // per-jt row pointers (k-offsets fold to immediates: kt*64B <= 960)
  const short* ps[8];
  #pragma unroll
  for (int jt = 0; jt < 8; ++jt)
    ps[jt] = Wb + (jb + jt * 16 + lr) * 512 + lk * 8;

  // AGPR-resident W: jt 0..6, kt 0..7 -> 56 short8 = 224 AGPRs
  short8 wa[7][8];
  #pragma unroll
  for (int jt = 0; jt < 7; ++jt)
    #pragma unroll
    for (int kt = 0; kt < 8; ++kt) {
      wa[jt][kt] = *(const short8*)(ps[jt] + kt * 32);
      asm volatile("" : "+a"(wa[jt][kt]));   // AGPR class; blocks remat/sink
    }
  // arch-resident W: jt 7, kt 0..7 -> 32 VGPRs
  short8 wv[8];
  #pragma unroll
  for (int kt = 0; kt < 8; ++kt) {
    wv[kt] = *(const short8*)(ps[7] + kt * 32);
    asm volatile("" : "+v"(wv[kt]));
  }

  // LDS W: k in [256,384): 512 rows x 16 short8-chunks
  for (int c = 0; c < 32; ++c) {
    int idx = c * 256 + tid;
    int j = idx >> 4, ch = idx & 15;
    *(short8*)&w_lds[j][ch * 8] = *(const short8*)(Wb + j * 512 + 256 + ch * 8);
  }

  float h[8][4];
  #pragma unroll
  for (int jt = 0; jt < 8; ++jt)
    #pragma unroll
    for (int q = 0; q < 4; ++q) h[jt][q] = 0.f;

  const size_t base = (size_t)(g * 16 + lk * 4) * 524288 + jb + lr;
  __syncthreads();

  f32x4 acc[8];
  // prologue: acc <- xu[t=0] (xu folded into MFMA C-operand)
  {
    const float* p = out + base;
    #pragma unroll
    for (int jt = 0; jt < 8; ++jt)
      #pragma unroll
      for (int q = 0; q < 4; ++q)
        acc[jt][q] = p[(size_t)q * 524288 + jt * 16];
  }

  for (int t = 0; t < 1024; ++t) {
    // A = tanh(h) -> bf16 staging
    #pragma unroll
    for (int jt = 0; jt < 8; ++jt)
      #pragma unroll
      for (int q = 0; q < 4; ++q)
        a_lds[lk * 4 + q][jb + jt * 16 + lr] = f2bf(tanh_fast(h[jt][q]));
    __syncthreads();

    // issue stream kt12/kt13 (depth-2 rotating buffer)
    short8 s0[8], s1[8];
    #pragma unroll
    for (int jt = 0; jt < 8; ++jt) s0[jt] = *(const short8*)(ps[jt] + 12 * 32);
    #pragma unroll
    for (int jt = 0; jt < 8; ++jt) s1[jt] = *(const short8*)(ps[jt] + 13 * 32);

    // LDS kt 8,9 (their ds_reads also hide the stream-issue latency)
    #pragma unroll
    for (int kt = 8; kt < 10; ++kt) {
      short8 a8 = *(const short8*)&a_lds[lr][kt * 32 + lk * 8];
      #pragma unroll
      for (int jt = 0; jt < 8; ++jt) {
        short8 b = *(const short8*)&w_lds[jb + jt * 16 + lr][(kt - 8) * 32 + lk * 8];
        acc[jt] = __builtin_amdgcn_mfma_f32_16x16x32_bf16(a8, b, acc[jt], 0, 0, 0);
      }
    }
    // stream kt12; refill s0 <- kt14
    {
      short8 a8 = *(const short8*)&a_lds[lr][12 * 32 + lk * 8];
      #pragma unroll
      for (int jt = 0; jt < 8; ++jt)
        acc[jt] = __builtin_amdgcn_mfma_f32_16x16x32_bf16(a8, s0[jt], acc[jt], 0, 0, 0);
      #pragma unroll
      for (int jt = 0; jt < 8; ++jt) s0[jt] = *(const short8*)(ps[jt] + 14 * 32);
    }
    // AGPR/arch kt 0..3
    #pragma unroll
    for (int kt = 0; kt < 4; ++kt) {
      short8 a8 = *(const short8*)&a_lds[lr][kt * 32 + lk * 8];
      #pragma unroll
      for (int jt = 0; jt < 7; ++jt)
        acc[jt] = __builtin_amdgcn_mfma_f32_16x16x32_bf16(a8, wa[jt][kt], acc[jt], 0, 0, 0);
      acc[7] = __builtin_amdgcn_mfma_f32_16x16x32_bf16(a8, wv[kt], acc[7], 0, 0, 0);
    }
    // stream kt13; refill s1 <- kt15
    {
      short8 a8 = *(const short8*)&a_lds[lr][13 * 32 + lk * 8];
      #pragma unroll
      for (int jt = 0; jt < 8; ++jt)
        acc[jt] = __builtin_amdgcn_mfma_f32_16x16x32_bf16(a8, s1[jt], acc[jt], 0, 0, 0);
      #pragma unroll
      for (int jt = 0; jt < 8; ++jt) s1[jt] = *(const short8*)(ps[jt] + 15 * 32);
    }
    // AGPR/arch kt 4..7
    #pragma unroll
    for (int kt = 4; kt < 8; ++kt) {
      short8 a8 = *(const short8*)&a_lds[lr][kt * 32 + lk * 8];
      #pragma unroll
      for (int jt = 0; jt < 7; ++jt)
        acc[jt] = __builtin_amdgcn_mfma_f32_16x16x32_bf16(a8, wa[jt][kt], acc[jt], 0, 0, 0);
      acc[7] = __builtin_amdgcn_mfma_f32_16x16x32_bf16(a8, wv[kt], acc[7], 0, 0, 0);
    }
    // LDS kt 10,11
    #pragma unroll
    for (int kt = 10; kt < 12; ++kt) {
      short8 a8 = *(const short8*)&a_lds[lr][kt * 32 + lk * 8];
      #pragma unroll
      for (int jt = 0; jt < 8; ++jt) {
        short8 b = *(const short8*)&w_lds[jb + jt * 16 + lr][(kt - 8) * 32 + lk * 8];
        acc[jt] = __builtin_amdgcn_mfma_f32_16x16x32_bf16(a8, b, acc[jt], 0, 0, 0);
      }
    }
    // stream kt14, kt15
    {
      short8 a8 = *(const short8*)&a_lds[lr][14 * 32 + lk * 8];
      #pragma unroll
      for (int jt = 0; jt < 8; ++jt)
        acc[jt] = __builtin_amdgcn_mfma_f32_16x16x32_bf16(a8, s0[jt], acc[jt], 0, 0, 0);
    }
    {
      short8 a8 = *(const short8*)&a_lds[lr][15 * 32 + lk * 8];
      #pragma unroll
      for (int jt = 0; jt < 8; ++jt)
        acc[jt] = __builtin_amdgcn_mfma_f32_16x16x32_bf16(a8, s1[jt], acc[jt], 0, 0, 0);
    }

    // h' = 0.9*h + 0.1*acc; store in place over xu[t]
    float* po = out + base + (size_t)t * 512;
    #pragma unroll
    for (int jt = 0; jt < 8; ++jt)
      #pragma unroll
      for (int q = 0; q < 4; ++q) {
        float v = 0.9f * h[jt][q] + 0.1f * acc[jt][q];
        h[jt][q] = v;
        po[(size_t)q * 524288 + jt * 16] = v;
      }
    __syncthreads();  // a_lds reads done before next iteration's writes

    // tail: prefetch next step's xu into acc (hides L3 latency)
    int tn = t + 1; if (tn > 1023) tn = 1023;
    const float* pn = out + base + (size_t)tn * 512;
    #pragma unroll
    for (int jt = 0; jt < 8; ++jt)
      #pragma unroll
      for (int q = 0; q < 4; ++q)
        acc[jt][q] = pn[(size_t)q * 524288 + jt * 16];
  }
}

// ----------------------------------------------------------------
extern "C" void kernel_launch(void* const* d_in, const int* in_sizes, int n_in,
                              void* d_out, int out_size, void* d_ws, size_t ws_size,
                              hipStream_t stream) {
  (void)in_sizes; (void)n_in; (void)out_size; (void)ws_size;
  const float* x = (const float*)d_in[0];
  const float* W = (const float*)d_in[1];
  const float* U = (const float*)d_in[2];
  float* out = (float*)d_out;
  short* Wb = (short*)d_ws;
  short* Ub = Wb + 512 * 512;

  convert_wu<<<384, 256, 0, stream>>>(W, U, Wb, Ub);
  xu_gemm<<<2048, 256, 0, stream>>>(x, Ub, out);
  rnn_scan<<<4, 256, 0, stream>>>(Wb, out);
}

// Round 11
// 3496.217 us; speedup vs baseline: 2.5722x; 1.2373x over previous
//
#include <hip/hip_runtime.h>

typedef __attribute__((ext_vector_type(4))) float f32x4;
typedef __attribute__((ext_vector_type(8))) short short8;
typedef __attribute__((ext_vector_type(4))) short short4_t;

__device__ __forceinline__ short f2bf(float f) {
  unsigned u = __float_as_uint(f);
  u += 0x7fffu + ((u >> 16) & 1u);   // round-to-nearest-even
  return (short)(u >> 16);
}

__device__ __forceinline__ float tanh_fast(float x) {
  float e = __expf(2.0f * x);
  return 1.0f - __fdividef(2.0f, e + 1.0f);
}

// ---------------------------------------------------------------- convert W,U -> bf16
__global__ __launch_bounds__(256) void convert_wu(
    const float* __restrict__ W, const float* __restrict__ U,
    short* __restrict__ Wb, short* __restrict__ Ub) {
  int i = blockIdx.x * 256 + threadIdx.x;
  if (i < 65536) {
    f32x4 v = ((const f32x4*)W)[i];
    short4_t s;
    s.x = f2bf(v.x); s.y = f2bf(v.y); s.z = f2bf(v.z); s.w = f2bf(v.w);
    ((short4_t*)Wb)[i] = s;
  } else if (i < 98304) {
    int k = i - 65536;
    f32x4 v = ((const f32x4*)U)[k];
    short4_t s;
    s.x = f2bf(v.x); s.y = f2bf(v.y); s.z = f2bf(v.z); s.w = f2bf(v.w);
    ((short4_t*)Ub)[k] = s;
  }
}

// ---------------------------------------------------------------- xu = x @ U^T  (bf16 MFMA)
__global__ __launch_bounds__(256) void xu_gemm(
    const float* __restrict__ x, const short* __restrict__ Ub,
    float* __restrict__ out) {
  __shared__ __attribute__((aligned(16))) short a_lds[128][272];
  __shared__ __attribute__((aligned(16))) short b_lds[128][272];
  const int tid = threadIdx.x;
  const int mb = blockIdx.x >> 2;
  const int nb = blockIdx.x & 3;

  const float* xb = x + (size_t)mb * (128 * 256);
  for (int c = 0; c < 32; ++c) {
    int idx = c * 256 + tid;
    int r = idx >> 6, c4 = idx & 63;
    f32x4 v = ((const f32x4*)xb)[idx];
    short4_t s;
    s.x = f2bf(v.x); s.y = f2bf(v.y); s.z = f2bf(v.z); s.w = f2bf(v.w);
    *(short4_t*)&a_lds[r][c4 * 4] = s;
  }
  const short* ub = Ub + nb * (128 * 256);
  for (int c = 0; c < 16; ++c) {
    int idx = c * 256 + tid;
    int r = idx >> 5, ch = idx & 31;
    *(short8*)&b_lds[r][ch * 8] = ((const short8*)ub)[idx];
  }
  __syncthreads();

  const int lane = tid & 63, wave = tid >> 6;
  const int wr = wave >> 1, wc = wave & 1;
  const int lr = lane & 15, lk = lane >> 4;
  const f32x4 zero = {0.f, 0.f, 0.f, 0.f};
  f32x4 acc[4][4];
  #pragma unroll
  for (int mt = 0; mt < 4; ++mt)
    #pragma unroll
    for (int nt = 0; nt < 4; ++nt) acc[mt][nt] = zero;

  #pragma unroll
  for (int kt = 0; kt < 8; ++kt) {
    const int k = kt * 32 + lk * 8;
    short8 a[4], b[4];
    #pragma unroll
    for (int mt = 0; mt < 4; ++mt)
      a[mt] = *(const short8*)&a_lds[wr * 64 + mt * 16 + lr][k];
    #pragma unroll
    for (int nt = 0; nt < 4; ++nt)
      b[nt] = *(const short8*)&b_lds[wc * 64 + nt * 16 + lr][k];
    #pragma unroll
    for (int mt = 0; mt < 4; ++mt)
      #pragma unroll
      for (int nt = 0; nt < 4; ++nt)
        acc[mt][nt] = __builtin_amdgcn_mfma_f32_16x16x32_bf16(a[mt], b[nt], acc[mt][nt], 0, 0, 0);
  }

  #pragma unroll
  for (int mt = 0; mt < 4; ++mt)
    #pragma unroll
    for (int nt = 0; nt < 4; ++nt)
      #pragma unroll
      for (int q = 0; q < 4; ++q) {
        int row = mb * 128 + wr * 64 + mt * 16 + lk * 4 + q;
        int col = nb * 128 + wc * 64 + nt * 16 + lr;
        out[(size_t)row * 512 + col] = acc[mt][nt][q];
      }
}

// ---------------------------------------------------------------- recurrence scan
// 4 blocks x 512 threads (8 waves = 2/SIMD for TLP; 1 block/CU via 152KB LDS).
// Register model settled by R9/R10: pool = 512 regs/lane/SIMD; at 2 waves/SIMD
// each wave gets 256 COMBINED (arch+AGPR). R7 uses 120 arch -> 136 AGPRs of
// headroom never exploited. W residency per wave (owns 64 j-cols):
//   kt 0..1  : 64 arch VGPRs ("+v" pin, proven R7)
//   kt 2..4  : 96 AGPRs      ("+a" pin; correctness proven R10 at legal budget;
//                              R4's NaN was an over-budget ask)
//   kt 5..8  : LDS (128KB)
//   kt 9..15 : streamed from L2, 224KB/step (vs R7's 320KB), depth-2 rotation
// Step model: stream 224KB@60B/cyc=3700cyc (bound) || LDS 1000 || MFMA 2483.
__global__ __launch_bounds__(512, 2) void rnn_scan(
    const short* __restrict__ Wb, float* __restrict__ out) {
  __shared__ __attribute__((aligned(16))) short w_lds[512][136];  // k 160..288
  __shared__ __attribute__((aligned(16))) short a_lds[16][520];   // tanh(h) bf16
  const int tid = threadIdx.x;
  const int blk = blockIdx.x;
  const int lane = tid & 63, wave = tid >> 6;
  const int j0 = wave * 64;
  const int lr = lane & 15, lk = lane >> 4;

  // per-jt row pointers (kt offsets fold to immediates)
  const short* pj[4];
  #pragma unroll
  for (int jt = 0; jt < 4; ++jt)
    pj[jt] = Wb + (j0 + jt * 16 + lr) * 512 + lk * 8;

  // arch-resident W: kt 0..1 (64 VGPRs)
  short8 wreg[4][2];
  #pragma unroll
  for (int jt = 0; jt < 4; ++jt)
    #pragma unroll
    for (int kt = 0; kt < 2; ++kt) {
      wreg[jt][kt] = *(const short8*)(pj[jt] + kt * 32);
      asm volatile("" : "+v"(wreg[jt][kt]));
    }
  // AGPR-resident W: kt 2..4 (96 AGPRs)
  short8 wa[4][3];
  #pragma unroll
  for (int jt = 0; jt < 4; ++jt)
    #pragma unroll
    for (int kt = 0; kt < 3; ++kt) {
      wa[jt][kt] = *(const short8*)(pj[jt] + (kt + 2) * 32);
      asm volatile("" : "+a"(wa[jt][kt]));
    }

  // LDS-resident W: k in [160,288) (kt 5..8): 512 rows x 16 short8-chunks
  for (int c = 0; c < 16; ++c) {
    int idx = c * 512 + tid;
    int j = idx >> 4, ch = idx & 15;
    *(short8*)&w_lds[j][ch * 8] = *(const short8*)(Wb + j * 512 + 160 + ch * 8);
  }

  float h[4][4];
  #pragma unroll
  for (int jt = 0; jt < 4; ++jt)
    #pragma unroll
    for (int q = 0; q < 4; ++q) h[jt][q] = 0.f;

  const size_t base = (size_t)(blk * 16 + lk * 4) * 524288 + j0 + lr;
  __syncthreads();

  f32x4 acc[4];
  // prologue: acc <- xu[t=0]
  {
    const float* p = out + base;
    #pragma unroll
    for (int jt = 0; jt < 4; ++jt)
      #pragma unroll
      for (int q = 0; q < 4; ++q)
        acc[jt][q] = p[(size_t)q * 524288 + jt * 16];
  }

  for (int t = 0; t < 1024; ++t) {
    // A = tanh(h) -> bf16 staging
    #pragma unroll
    for (int jt = 0; jt < 4; ++jt)
      #pragma unroll
      for (int q = 0; q < 4; ++q)
        a_lds[lk * 4 + q][j0 + jt * 16 + lr] = f2bf(tanh_fast(h[jt][q]));
    __syncthreads();

    // issue stream kt9/kt10 (depth-2 rotation s0/s1)
    short8 s0[4], s1[4];
    #pragma unroll
    for (int jt = 0; jt < 4; ++jt) s0[jt] = *(const short8*)(pj[jt] + 9 * 32);
    #pragma unroll
    for (int jt = 0; jt < 4; ++jt) s1[jt] = *(const short8*)(pj[jt] + 10 * 32);

    // no-memory phases cover the stream latency: arch kt0..1, AGPR kt2..4
    #pragma unroll
    for (int kt = 0; kt < 2; ++kt) {
      short8 a8 = *(const short8*)&a_lds[lr][kt * 32 + lk * 8];
      #pragma unroll
      for (int jt = 0; jt < 4; ++jt)
        acc[jt] = __builtin_amdgcn_mfma_f32_16x16x32_bf16(a8, wreg[jt][kt], acc[jt], 0, 0, 0);
    }
    #pragma unroll
    for (int kt = 0; kt < 3; ++kt) {
      short8 a8 = *(const short8*)&a_lds[lr][(kt + 2) * 32 + lk * 8];
      #pragma unroll
      for (int jt = 0; jt < 4; ++jt)
        acc[jt] = __builtin_amdgcn_mfma_f32_16x16x32_bf16(a8, wa[jt][kt], acc[jt], 0, 0, 0);
    }
    // kt9 (s0); refill s0 <- kt11
    {
      short8 a8 = *(const short8*)&a_lds[lr][9 * 32 + lk * 8];
      #pragma unroll
      for (int jt = 0; jt < 4; ++jt)
        acc[jt] = __builtin_amdgcn_mfma_f32_16x16x32_bf16(a8, s0[jt], acc[jt], 0, 0, 0);
      #pragma unroll
      for (int jt = 0; jt < 4; ++jt) s0[jt] = *(const short8*)(pj[jt] + 11 * 32);
    }
    // LDS kt5, kt6
    #pragma unroll
    for (int kt = 5; kt < 7; ++kt) {
      short8 a8 = *(const short8*)&a_lds[lr][kt * 32 + lk * 8];
      #pragma unroll
      for (int jt = 0; jt < 4; ++jt) {
        short8 b = *(const short8*)&w_lds[j0 + jt * 16 + lr][(kt - 5) * 32 + lk * 8];
        acc[jt] = __builtin_amdgcn_mfma_f32_16x16x32_bf16(a8, b, acc[jt], 0, 0, 0);
      }
    }
    // kt10 (s1); refill s1 <- kt12
    {
      short8 a8 = *(const short8*)&a_lds[lr][10 * 32 + lk * 8];
      #pragma unroll
      for (int jt = 0; jt < 4; ++jt)
        acc[jt] = __builtin_amdgcn_mfma_f32_16x16x32_bf16(a8, s1[jt], acc[jt], 0, 0, 0);
      #pragma unroll
      for (int jt = 0; jt < 4; ++jt) s1[jt] = *(const short8*)(pj[jt] + 12 * 32);
    }
    // LDS kt7, kt8
    #pragma unroll
    for (int kt = 7; kt < 9; ++kt) {
      short8 a8 = *(const short8*)&a_lds[lr][kt * 32 + lk * 8];
      #pragma unroll
      for (int jt = 0; jt < 4; ++jt) {
        short8 b = *(const short8*)&w_lds[j0 + jt * 16 + lr][(kt - 5) * 32 + lk * 8];
        acc[jt] = __builtin_amdgcn_mfma_f32_16x16x32_bf16(a8, b, acc[jt], 0, 0, 0);
      }
    }
    // kt11 (s0); refill s0 <- kt13
    {
      short8 a8 = *(const short8*)&a_lds[lr][11 * 32 + lk * 8];
      #pragma unroll
      for (int jt = 0; jt < 4; ++jt)
        acc[jt] = __builtin_amdgcn_mfma_f32_16x16x32_bf16(a8, s0[jt], acc[jt], 0, 0, 0);
      #pragma unroll
      for (int jt = 0; jt < 4; ++jt) s0[jt] = *(const short8*)(pj[jt] + 13 * 32);
    }
    // kt12 (s1); refill s1 <- kt14
    {
      short8 a8 = *(const short8*)&a_lds[lr][12 * 32 + lk * 8];
      #pragma unroll
      for (int jt = 0; jt < 4; ++jt)
        acc[jt] = __builtin_amdgcn_mfma_f32_16x16x32_bf16(a8, s1[jt], acc[jt], 0, 0, 0);
      #pragma unroll
      for (int jt = 0; jt < 4; ++jt) s1[jt] = *(const short8*)(pj[jt] + 14 * 32);
    }
    // kt13 (s0); refill s0 <- kt15
    {
      short8 a8 = *(const short8*)&a_lds[lr][13 * 32 + lk * 8];
      #pragma unroll
      for (int jt = 0; jt < 4; ++jt)
        acc[jt] = __builtin_amdgcn_mfma_f32_16x16x32_bf16(a8, s0[jt], acc[jt], 0, 0, 0);
      #pragma unroll
      for (int jt = 0; jt < 4; ++jt) s0[jt] = *(const short8*)(pj[jt] + 15 * 32);
    }
    // kt14 (s1), kt15 (s0)
    {
      short8 a8 = *(const short8*)&a_lds[lr][14 * 32 + lk * 8];
      #pragma unroll
      for (int jt = 0; jt < 4; ++jt)
        acc[jt] = __builtin_amdgcn_mfma_f32_16x16x32_bf16(a8, s1[jt], acc[jt], 0, 0, 0);
    }
    {
      short8 a8 = *(const short8*)&a_lds[lr][15 * 32 + lk * 8];
      #pragma unroll
      for (int jt = 0; jt < 4; ++jt)
        acc[jt] = __builtin_amdgcn_mfma_f32_16x16x32_bf16(a8, s0[jt], acc[jt], 0, 0, 0);
    }

    // h' = 0.9*h + 0.1*acc; store in place over xu[t]
    float* po = out + base + (size_t)t * 512;
    #pragma unroll
    for (int jt = 0; jt < 4; ++jt)
      #pragma unroll
      for (int q = 0; q < 4; ++q) {
        float v = 0.9f * h[jt][q] + 0.1f * acc[jt][q];
        h[jt][q] = v;
        po[(size_t)q * 524288 + jt * 16] = v;
      }
    __syncthreads();  // a_lds reads done before next iteration's writes

    // tail: prefetch next step's xu into acc (hides L3 latency)
    int tn = t + 1; if (tn > 1023) tn = 1023;
    const float* pn = out + base + (size_t)tn * 512;
    #pragma unroll
    for (int jt = 0; jt < 4; ++jt)
      #pragma unroll
      for (int q = 0; q < 4; ++q)
        acc[jt][q] = pn[(size_t)q * 524288 + jt * 16];
  }
}

// ----------------------------------------------------------------
extern "C" void kernel_launch(void* const* d_in, const int* in_sizes, int n_in,
                              void* d_out, int out_size, void* d_ws, size_t ws_size,
                              hipStream_t stream) {
  (void)in_sizes; (void)n_in; (void)out_size; (void)ws_size;
  const float* x = (const float*)d_in[0];
  const float* W = (const float*)d_in[1];
  const float* U = (const float*)d_in[2];
  float* out = (float*)d_out;
  short* Wb = (short*)d_ws;
  short* Ub = Wb + 512 * 512;

  convert_wu<<<384, 256, 0, stream>>>(W, U, Wb, Ub);
  xu_gemm<<<2048, 256, 0, stream>>>(x, Ub, out);
  rnn_scan<<<4, 512, 0, stream>>>(Wb, out);
}